// Round 1
// baseline (3282.013 us; speedup 1.0000x reference)
//
#include <hip/hip_runtime.h>
#include <hip/hip_bf16.h>
#include <math.h>

// Problem constants
#define BATCH   2
#define NTOK    2048
#define DMODEL  1024
#define HEADS   16
#define DHEAD   64
#define KSEL    32
#define MROWS   (BATCH * NTOK)   // 4096

// ---------------------------------------------------------------------------
// GEMM: C[m,o] = sum_k A[m,k] * W[o,k] + bias[o]
//   A: [MROWS, 1024] row-major, W: [1024, 1024] row-major (torch Linear W)
//   scatter==0: out[m*1024 + o]
//   scatter==1: out written as [b, h, n, d] with b=m>>11, n=m&2047, h=o>>6, d=o&63
// 64x64 tile, BK=16, 256 threads, 4x4 micro-tile per thread.
// ---------------------------------------------------------------------------
__global__ __launch_bounds__(256) void gemm_nt(const float* __restrict__ A,
                                               const float* __restrict__ W,
                                               const float* __restrict__ bias,
                                               float* __restrict__ out,
                                               int scatter)
{
    __shared__ float As[16][65];  // As[k][m]
    __shared__ float Bs[16][65];  // Bs[k][o]

    const int tid = threadIdx.x;
    const int bm = blockIdx.x * 64;
    const int bo = blockIdx.y * 64;
    const int tx = tid & 15;       // 0..15 -> output col group
    const int ty = tid >> 4;       // 0..15 -> output row group

    const int lr = tid >> 2;          // 0..63 tile row for loads
    const int lc = (tid & 3) << 2;    // 0,4,8,12 k-offset for float4 load

    float acc[4][4];
#pragma unroll
    for (int i = 0; i < 4; ++i)
#pragma unroll
        for (int j = 0; j < 4; ++j) acc[i][j] = 0.f;

    for (int k0 = 0; k0 < DMODEL; k0 += 16) {
        float4 av = *(const float4*)(A + (size_t)(bm + lr) * DMODEL + k0 + lc);
        float4 bv = *(const float4*)(W + (size_t)(bo + lr) * DMODEL + k0 + lc);
        As[lc + 0][lr] = av.x; As[lc + 1][lr] = av.y;
        As[lc + 2][lr] = av.z; As[lc + 3][lr] = av.w;
        Bs[lc + 0][lr] = bv.x; Bs[lc + 1][lr] = bv.y;
        Bs[lc + 2][lr] = bv.z; Bs[lc + 3][lr] = bv.w;
        __syncthreads();
#pragma unroll
        for (int kk = 0; kk < 16; ++kk) {
            float a0 = As[kk][ty * 4 + 0];
            float a1 = As[kk][ty * 4 + 1];
            float a2 = As[kk][ty * 4 + 2];
            float a3 = As[kk][ty * 4 + 3];
            float b0 = Bs[kk][tx * 4 + 0];
            float b1 = Bs[kk][tx * 4 + 1];
            float b2 = Bs[kk][tx * 4 + 2];
            float b3 = Bs[kk][tx * 4 + 3];
            acc[0][0] += a0 * b0; acc[0][1] += a0 * b1; acc[0][2] += a0 * b2; acc[0][3] += a0 * b3;
            acc[1][0] += a1 * b0; acc[1][1] += a1 * b1; acc[1][2] += a1 * b2; acc[1][3] += a1 * b3;
            acc[2][0] += a2 * b0; acc[2][1] += a2 * b1; acc[2][2] += a2 * b2; acc[2][3] += a2 * b3;
            acc[3][0] += a3 * b0; acc[3][1] += a3 * b1; acc[3][2] += a3 * b2; acc[3][3] += a3 * b3;
        }
        __syncthreads();
    }

#pragma unroll
    for (int i = 0; i < 4; ++i) {
        const int m = bm + ty * 4 + i;
#pragma unroll
        for (int j = 0; j < 4; ++j) {
            const int o = bo + tx * 4 + j;
            const float v = acc[i][j] + bias[o];
            if (scatter) {
                const int bb = m >> 11;       // batch
                const int n  = m & 2047;      // token
                const int h  = o >> 6;        // head
                const int d  = o & 63;        // dim
                out[(((size_t)(bb * HEADS + h)) * NTOK + n) * DHEAD + d] = v;
            } else {
                out[(size_t)m * DMODEL + o] = v;
            }
        }
    }
}

// ---------------------------------------------------------------------------
// Fused attention: one block per (b, q). 4 waves; wave w handles heads
// w, 4+w, 8+w, 12+w. Per head: scores (causal, scaled), top-32 by iterative
// wave argmax extraction, softmax over selected, ctx = sum w_i * V[idx_i].
// attn-mean accumulated in LDS (atomicAdd) and written densely.
// ---------------------------------------------------------------------------
__global__ __launch_bounds__(256) void attn_kernel(const float* __restrict__ Q,
                                                   const float* __restrict__ K,
                                                   const float* __restrict__ V,
                                                   float* __restrict__ ctx,
                                                   float* __restrict__ attn_out)
{
    const int blk = blockIdx.x;
    const int b = blk >> 11;        // / NTOK
    const int q = blk & (NTOK - 1);
    const int tid = threadIdx.x;
    const int wave = tid >> 6;
    const int lane = tid & 63;

    __shared__ float sc[4][NTOK];       // per-wave score buffer (32 KB)
    __shared__ float am[NTOK];          // attn-mean accumulator (8 KB)
    __shared__ float selv[4][KSEL];
    __shared__ int   seli[4][KSEL];
    __shared__ float selw[4][KSEL];

    for (int j = tid; j < NTOK; j += 256) am[j] = 0.f;
    __syncthreads();

    const int L = q + 1;
    const int nsel = (L < KSEL) ? L : KSEL;

    for (int hg = 0; hg < 4; ++hg) {
        const int h = hg * 4 + wave;
        const size_t bh = (size_t)(b * HEADS + h);
        const float* Qrow = Q + (bh * NTOK + q) * DHEAD;
        const float* Kb = K + bh * NTOK * DHEAD;
        const float* Vb = V + bh * NTOK * DHEAD;

        // q vector into registers (broadcast load, L1-served)
        float4 qr[16];
#pragma unroll
        for (int d4 = 0; d4 < 16; ++d4) qr[d4] = ((const float4*)Qrow)[d4];

        // scores for j = lane, lane+64, ... ; track per-lane local max
        float lm = -INFINITY; int li = -1;
        for (int j = lane; j < L; j += 64) {
            const float4* kr = (const float4*)(Kb + (size_t)j * DHEAD);
            float a0 = 0.f, a1 = 0.f, a2 = 0.f, a3 = 0.f;
#pragma unroll
            for (int d4 = 0; d4 < 16; ++d4) {
                const float4 kk = kr[d4];
                a0 += qr[d4].x * kk.x;
                a1 += qr[d4].y * kk.y;
                a2 += qr[d4].z * kk.z;
                a3 += qr[d4].w * kk.w;
            }
            const float s = (a0 + a1 + a2 + a3) * 0.125f;
            sc[wave][j] = s;
            if (s > lm) { lm = s; li = j; }
        }

        // iterative top-nsel extraction (wave-synchronous, no block barrier)
        for (int it = 0; it < nsel; ++it) {
            float bmv = lm; int bi = li;
#pragma unroll
            for (int mask = 1; mask < 64; mask <<= 1) {
                const float ov = __shfl_xor(bmv, mask, 64);
                const int   oi = __shfl_xor(bi, mask, 64);
                if (ov > bmv || (ov == bmv && (unsigned)oi < (unsigned)bi)) {
                    bmv = ov; bi = oi;
                }
            }
            // all lanes now agree on (bmv, bi)
            if (lane == (bi & 63)) {
                sc[wave][bi] = -INFINITY;
                // recompute this lane's local max
                lm = -INFINITY; li = -1;
                for (int j = lane; j < L; j += 64) {
                    const float s = sc[wave][j];
                    if (s > lm) { lm = s; li = j; }
                }
            }
            if (lane == 0) { selv[wave][it] = bmv; seli[wave][it] = bi; }
        }

        // softmax over the selected set (max = first extracted)
        const float m = selv[wave][0];
        float e = 0.f;
        if (lane < nsel) e = expf(selv[wave][lane] - m);
        float Z = e;
#pragma unroll
        for (int mask = 1; mask < 32; mask <<= 1) Z += __shfl_xor(Z, mask, 64);
        if (lane < nsel) {
            const float w = e / Z;
            selw[wave][lane] = w;
            atomicAdd(&am[seli[wave][lane]], w);
        }

        // ctx[b,q,h,:] = sum_i w_i * V[b,h,idx_i,:]   (lane = d)
        float acc = 0.f;
        for (int i = 0; i < nsel; ++i) {
            const int idx = seli[wave][i];
            const float w = selw[wave][i];
            acc += w * Vb[(size_t)idx * DHEAD + lane];
        }
        ctx[(((size_t)(b * NTOK + q)) * HEADS + h) * DHEAD + lane] = acc;
    }

    __syncthreads();
    const float invH = 1.0f / (float)HEADS;
    float* arow = attn_out + ((size_t)(b * NTOK + q)) * NTOK;
    for (int j = tid; j < NTOK; j += 256) arow[j] = am[j] * invH;
}

// ---------------------------------------------------------------------------
extern "C" void kernel_launch(void* const* d_in, const int* in_sizes, int n_in,
                              void* d_out, int out_size, void* d_ws, size_t ws_size,
                              hipStream_t stream) {
    const float* x  = (const float*)d_in[0];
    const float* Wq = (const float*)d_in[1];
    const float* bq = (const float*)d_in[2];
    const float* Wk = (const float*)d_in[3];
    const float* bk = (const float*)d_in[4];
    const float* Wv = (const float*)d_in[5];
    const float* bv = (const float*)d_in[6];
    const float* Wo = (const float*)d_in[7];
    const float* bo = (const float*)d_in[8];

    const size_t SZ = (size_t)MROWS * DMODEL;  // 4,194,304 floats
    float* ws  = (float*)d_ws;
    float* Qws = ws;
    float* Kws = ws + SZ;
    float* Vws = ws + 2 * SZ;
    float* ctx = ws + 3 * SZ;

    float* y    = (float*)d_out;                     // [B, N, DMODEL]
    float* attn = y + (size_t)BATCH * NTOK * DMODEL; // [B, N, N]

    dim3 gemm_grid(MROWS / 64, DMODEL / 64);
    gemm_nt<<<gemm_grid, 256, 0, stream>>>(x, Wq, bq, Qws, 1);
    gemm_nt<<<gemm_grid, 256, 0, stream>>>(x, Wk, bk, Kws, 1);
    gemm_nt<<<gemm_grid, 256, 0, stream>>>(x, Wv, bv, Vws, 1);

    attn_kernel<<<BATCH * NTOK, 256, 0, stream>>>(Qws, Kws, Vws, ctx, attn);

    gemm_nt<<<gemm_grid, 256, 0, stream>>>(ctx, Wo, bo, y, 0);
}